// Round 11
// baseline (68829.321 us; speedup 1.0000x reference)
//
#include <hip/hip_runtime.h>
#include <hip/hip_cooperative_groups.h>

namespace cg = cooperative_groups;

#define Bb   256   // batch
#define Tt   512   // time steps
#define INx  19    // input features
#define Hh   512   // hidden
#define NWG  256   // (unit-group 0..127) x (batch-half 0..1); 4 units, 128 batches each
#define NTHR 512   // 8 waves = (su 0..3) x (kq 0..1); lane = bg 0..63 (2 batches)

#define PART_FLOATS (8 * 12 * 128)       // [wid][12 rows][128 b] = 48 KiB
#define WX1_FLOATS  (16 * 20)            // 4 units x 4 gates x 19 (pad 20)
#define FCB_FLOATS  (Hh + 256 + 128)
#define SMEM_FLOATS (PART_FLOATS + WX1_FLOATS + FCB_FLOATS)
#define SMEM_BYTES  (SMEM_FLOATS * 4)

typedef unsigned int u32;
typedef unsigned long long u64;

__device__ __forceinline__ float sigf(float x) { return 1.0f / (1.0f + __expf(-x)); }
__device__ __forceinline__ float tanhfast(float x) {
    float e = __expf(2.0f * x);
    return 1.0f - 2.0f / (e + 1.0f);
}

union pcast { u64 u; float2 f; };
// h stores: agent-scope (LLC-visible once vmcnt drained). r9-proven path.
__device__ __forceinline__ void gstore2(float2* p, float2 v) {
    pcast c; c.f = v;
    __hip_atomic_store((u64*)p, c.u, __ATOMIC_RELAXED, __HIP_MEMORY_SCOPE_AGENT);
}

// Flag barrier; acquire fence (buffer_inv) executed by ONE wave per CU
// (L1 is per-CU, L2 per-XCD -> one inv covers all 8 waves; r10 showed
// redundant cache-maintenance ops are expensive).
__device__ __forceinline__ void gbar(u32* flags, int wgid, int tid, u32 phase) {
    __syncthreads();   // drains vmem stores of all waves before flag release
    if (tid == 0)
        __hip_atomic_store(&flags[wgid], phase, __ATOMIC_RELEASE, __HIP_MEMORY_SCOPE_AGENT);
    if (tid < NWG) {
        const u32* fp = &flags[tid];
        while (__hip_atomic_load(fp, __ATOMIC_RELAXED, __HIP_MEMORY_SCOPE_AGENT) < phase)
            __builtin_amdgcn_s_sleep(2);
    }
    __syncthreads();
    if (tid < 64)
        __builtin_amdgcn_fence(__ATOMIC_ACQUIRE, "agent");   // single buffer_inv
    __syncthreads();
}

// load chunk c (4 consecutive k's): one float4 per k = (h1,h2) pairs of the
// lane's 2 adjacent batches.
__device__ __forceinline__ void ldc(const float4* __restrict__ hp, int c,
                                    float4 (&H)[4]) {
    #pragma unroll
    for (int kk = 0; kk < 4; ++kk)
        H[kk] = hp[(size_t)c * 512 + (size_t)kk * 128];
}

// 96 FMA: 12 rows x 4 k x 2 batches. Weight pointers WAVE-UNIFORM -> s_load.
// H[kk] = (h1_b0, h2_b0, h1_b1, h2_b1) at k.
__device__ __forceinline__ void fmac(const float4 (&H)[4],
                                     const float* const (&wb1)[4],
                                     const float* const (&wb2)[4],
                                     const float* const (&wb3)[4], int koff,
                                     float (&a1)[4][2], float (&ax)[4][2], float (&ah)[4][2]) {
    #pragma unroll
    for (int g = 0; g < 4; ++g) {
        const float4 w1 = *reinterpret_cast<const float4*>(wb1[g] + koff);
        const float4 w2 = *reinterpret_cast<const float4*>(wb2[g] + koff);
        const float4 w3 = *reinterpret_cast<const float4*>(wb3[g] + koff);
        a1[g][0] += H[0].x*w1.x + H[1].x*w1.y + H[2].x*w1.z + H[3].x*w1.w;
        a1[g][1] += H[0].z*w1.x + H[1].z*w1.y + H[2].z*w1.z + H[3].z*w1.w;
        ax[g][0] += H[0].x*w2.x + H[1].x*w2.y + H[2].x*w2.z + H[3].x*w2.w;
        ax[g][1] += H[0].z*w2.x + H[1].z*w2.y + H[2].z*w2.z + H[3].z*w2.w;
        ah[g][0] += H[0].y*w3.x + H[1].y*w3.y + H[2].y*w3.z + H[3].y*w3.w;
        ah[g][1] += H[0].w*w3.x + H[1].w*w3.y + H[2].w*w3.z + H[3].w*w3.w;
    }
}

__global__ void __launch_bounds__(NTHR, 2)
lstm_fused(const float* __restrict__ input,
           const float* __restrict__ l1_Wx, const float* __restrict__ l1_bx,
           const float* __restrict__ l1_Wh, const float* __restrict__ l1_bh,
           const float* __restrict__ l2_Wx, const float* __restrict__ l2_bx,
           const float* __restrict__ l2_Wh, const float* __restrict__ l2_bh,
           const float* __restrict__ fc1_W, const float* __restrict__ fc1_b,
           const float* __restrict__ fc2_W, const float* __restrict__ fc2_b,
           const float* __restrict__ fc3_W, const float* __restrict__ fc3_b,
           float* __restrict__ out, float* __restrict__ ws)
{
    extern __shared__ float smem[];
    float* part = smem;                        // [8][12][128] K-partial exchange
    float* wx1l = smem + PART_FLOATS;          // [4u][4g][20]
    float* fcb  = wx1l + WX1_FLOATS;

    cg::grid_group grid = cg::this_grid();
    const int wgid = blockIdx.x;
    const int ug = wgid >> 1;        // unit-group 0..127
    const int bs = wgid & 1;         // batch-half
    const int jb = ug * 4;           // first owned unit
    const int tid = threadIdx.x;

    // sweep role: wave (su 0..3, kq 0..1); lane bg -> batches bs*128 + bg*2 (+1)
    const int wid = __builtin_amdgcn_readfirstlane(tid >> 6);
    const int su = wid >> 1;
    const int kq = wid & 1;
    const int bg = tid & 63;
    const int b0 = bs * 128 + bg * 2;
    // finish role: thread (fu 0..3, fb 0..127) -> unit jb+fu, batch bs*128+fb
    const int fu = tid >> 7;
    const int fb = tid & 127;
    const int bx = bs * 128 + fb;
    const int j2 = jb + fu;

    float2* PA = (float2*)ws;        // P[j][b] = (h1, h2)
    float2* PB = PA + Hh * Bb;
    u32* flags = (u32*)(PB + Hh * Bb);

    if (tid == 0)
        __hip_atomic_store(&flags[wgid], 0u, __ATOMIC_RELAXED, __HIP_MEMORY_SCOPE_AGENT);
    grid.sync();   // fences flag resets; the only runtime cg sync

    // ---- wave-uniform scalar weight row bases (s_load path) ----
    const float* wb1[4]; const float* wb2[4]; const float* wb3[4];
    {
        const int j = jb + su;
        #pragma unroll
        for (int g = 0; g < 4; ++g) {
            const size_t off = (size_t)(g * Hh + j) * Hh + kq * 256;
            wb1[g] = l1_Wh + off;
            wb2[g] = l2_Wx + off;
            wb3[g] = l2_Wh + off;
        }
    }

    // ---- stage tiny l1_Wx + biases ----
    if (tid < 16 * INx) {
        const int r = tid / INx, i = tid - r * INx;
        const int u = r >> 2, g = r & 3;
        wx1l[r * 20 + i] = l1_Wx[(size_t)(g * Hh + jb + u) * INx + i];
    }
    float b1r[4], b2r[4];
    #pragma unroll
    for (int g = 0; g < 4; ++g) {
        const int row = g * Hh + j2;
        b1r[g] = l1_bx[row] + l1_bh[row];
        b2r[g] = l2_bx[row] + l2_bh[row];
    }
    __syncthreads();

    // ---- prologue: P = (h1[0], h2[-1]=0), finish role ----
    float c1 = 0.f, c2 = 0.f;
    {
        const float* xr = input + (size_t)bx * Tt * INx;
        float s[4];
        #pragma unroll
        for (int g = 0; g < 4; ++g) {
            float acc = b1r[g];
            #pragma unroll
            for (int i = 0; i < INx; ++i) acc += xr[i] * wx1l[(fu * 4 + g) * 20 + i];
            s[g] = acc;
        }
        c1 = sigf(s[0]) * tanhfast(s[2]);
        gstore2(&PA[(size_t)j2 * Bb + bx], make_float2(sigf(s[3]) * tanhfast(c1), 0.f));
    }
    gbar(flags, wgid, tid, 1u);

    const float2* Pc = PA; float2* Pn = PB;

    for (int t = 0; t < Tt; ++t) {
        const bool doL1 = (t < Tt - 1);

        float a1[4][2], ax[4][2], ah[4][2];
        #pragma unroll
        for (int g = 0; g < 4; ++g)
            #pragma unroll
            for (int b = 0; b < 2; ++b) { a1[g][b] = 0.f; ax[g][b] = 0.f; ah[g][b] = 0.f; }

        // lane float4 base: per k the row has 128 float4s; kq selects k-half
        const float4* hp = (const float4*)Pc + (size_t)(kq * 256) * 128 + (b0 >> 1);

        // depth-4 software pipeline over 64 chunks of 4 k's
        float4 B0[4], B1[4], B2[4], B3[4];
        ldc(hp, 0, B0); ldc(hp, 1, B1); ldc(hp, 2, B2); ldc(hp, 3, B3);
        #pragma unroll 1
        for (int c = 0; c < 60; c += 4) {
            fmac(B0, wb1, wb2, wb3, (c + 0) * 4, a1, ax, ah); ldc(hp, c + 4, B0);
            fmac(B1, wb1, wb2, wb3, (c + 1) * 4, a1, ax, ah); ldc(hp, c + 5, B1);
            fmac(B2, wb1, wb2, wb3, (c + 2) * 4, a1, ax, ah); ldc(hp, c + 6, B2);
            fmac(B3, wb1, wb2, wb3, (c + 3) * 4, a1, ax, ah); ldc(hp, c + 7, B3);
        }
        fmac(B0, wb1, wb2, wb3, 240, a1, ax, ah);
        fmac(B1, wb1, wb2, wb3, 244, a1, ax, ah);
        fmac(B2, wb1, wb2, wb3, 248, a1, ax, ah);
        fmac(B3, wb1, wb2, wb3, 252, a1, ax, ah);

        // ---- K-partial exchange: 12 x ds_write_b64, ~conflict-free ----
        {
            float* pw = part + (size_t)(wid * 12) * 128 + bg * 2;
            #pragma unroll
            for (int g = 0; g < 4; ++g) {
                *reinterpret_cast<float2*>(pw + (0 + g) * 128) = make_float2(a1[g][0], a1[g][1]);
                *reinterpret_cast<float2*>(pw + (4 + g) * 128) = make_float2(ax[g][0], ax[g][1]);
                *reinterpret_cast<float2*>(pw + (8 + g) * 128) = make_float2(ah[g][0], ah[g][1]);
            }
        }

        // x[t+1] for finish (cached; issued before the sync)
        float xv[INx];
        if (doL1) {
            const float* xr = input + ((size_t)bx * Tt + t + 1) * INx;
            #pragma unroll
            for (int i = 0; i < INx; ++i) xv[i] = xr[i];
        }
        __syncthreads();

        // ---- finish: unit j2, batch bx; reduce 2 kq rowsets ----
        {
            float s1[4], s2[4];
            #pragma unroll
            for (int g = 0; g < 4; ++g) {
                const float* p0 = part + (size_t)((fu * 2 + 0) * 12) * 128 + fb;
                const float* p1 = part + (size_t)((fu * 2 + 1) * 12) * 128 + fb;
                s1[g] = p0[(0 + g) * 128] + p1[(0 + g) * 128] + b1r[g];
                s2[g] = p0[(4 + g) * 128] + p1[(4 + g) * 128]
                      + p0[(8 + g) * 128] + p1[(8 + g) * 128] + b2r[g];
            }
            float h1v = 0.f;
            if (doL1) {
                #pragma unroll
                for (int g = 0; g < 4; ++g) {
                    float acc = s1[g];
                    #pragma unroll
                    for (int i = 0; i < INx; ++i) acc += xv[i] * wx1l[(fu * 4 + g) * 20 + i];
                    s1[g] = acc;
                }
                const float ig = sigf(s1[0]), fg = sigf(s1[1]);
                const float gg = tanhfast(s1[2]), og = sigf(s1[3]);
                c1 = fg * c1 + ig * gg;
                h1v = og * tanhfast(c1);
            }
            const float ig = sigf(s2[0]), fg = sigf(s2[1]);
            const float gg = tanhfast(s2[2]), og = sigf(s2[3]);
            c2 = fg * c2 + ig * gg;
            gstore2(&Pn[(size_t)j2 * Bb + bx], make_float2(h1v, og * tanhfast(c2)));
        }

        gbar(flags, wgid, tid, (u32)(t + 2));

        const float2* tp = Pc; Pc = Pn; Pn = (float2*)tp;
    }
    // final h2 = Pc[.].y

    // ---------- FC head: WG wgid handles batch wgid (reuse smem) ----------
    float* hh  = fcb;
    float* a1s = fcb + Hh;
    float* a2s = fcb + Hh + 256;
    hh[tid] = Pc[(size_t)tid * Bb + wgid].y;   // cached, fresh post-fence
    __syncthreads();
    if (tid < 256) {
        float acc = fc1_b[tid];
        const float* wr = fc1_W + (size_t)tid * Hh;
        for (int i = 0; i < Hh; ++i) acc += wr[i] * hh[i];
        a1s[tid] = fmaxf(acc, 0.0f);
    }
    __syncthreads();
    if (tid < 128) {
        float acc = fc2_b[tid];
        const float* wr = fc2_W + (size_t)tid * 256;
        for (int i = 0; i < 256; ++i) acc += wr[i] * a1s[i];
        a2s[tid] = fmaxf(acc, 0.0f);
    }
    __syncthreads();
    if (tid == 0) {
        float acc = fc3_b[0];
        for (int i = 0; i < 128; ++i) acc += fc3_W[i] * a2s[i];
        out[wgid] = acc;
    }
}

extern "C" void kernel_launch(void* const* d_in, const int* in_sizes, int n_in,
                              void* d_out, int out_size, void* d_ws, size_t ws_size,
                              hipStream_t stream)
{
    (void)in_sizes; (void)n_in; (void)out_size; (void)ws_size;

    const float* input = (const float*)d_in[0];
    const float* l1_Wx = (const float*)d_in[1];
    const float* l1_bx = (const float*)d_in[2];
    const float* l1_Wh = (const float*)d_in[3];
    const float* l1_bh = (const float*)d_in[4];
    const float* l2_Wx = (const float*)d_in[5];
    const float* l2_bx = (const float*)d_in[6];
    const float* l2_Wh = (const float*)d_in[7];
    const float* l2_bh = (const float*)d_in[8];
    const float* fc1_W = (const float*)d_in[9];
    const float* fc1_b = (const float*)d_in[10];
    const float* fc2_W = (const float*)d_in[11];
    const float* fc2_b = (const float*)d_in[12];
    const float* fc3_W = (const float*)d_in[13];
    const float* fc3_b = (const float*)d_in[14];
    float* out = (float*)d_out;
    float* ws  = (float*)d_ws;

    hipFuncSetAttribute((const void*)lstm_fused,
                        hipFuncAttributeMaxDynamicSharedMemorySize, SMEM_BYTES);

    void* args[] = {
        &input,
        &l1_Wx, &l1_bx, &l1_Wh, &l1_bh,
        &l2_Wx, &l2_bx, &l2_Wh, &l2_bh,
        &fc1_W, &fc1_b, &fc2_W, &fc2_b, &fc3_W, &fc3_b,
        &out, &ws
    };
    hipLaunchCooperativeKernel((void*)lstm_fused, dim3(NWG), dim3(NTHR), args,
                               SMEM_BYTES, stream);
}

// Round 12
// 40713.446 us; speedup vs baseline: 1.6906x; 1.6906x over previous
//
#include <hip/hip_runtime.h>
#include <hip/hip_cooperative_groups.h>

namespace cg = cooperative_groups;

#define Bb   256   // batch
#define Tt   512   // time steps
#define INx  19    // input features
#define Hh   512   // hidden
#define NWG  256   // workgroups (2 units each), cooperative-proven grid
#define NTHR 512   // 8 waves = 8 independent batch streams (32 batches each)

typedef unsigned int u32;
typedef unsigned long long u64;

__device__ __forceinline__ float sigf(float x) { return 1.0f / (1.0f + __expf(-x)); }
__device__ __forceinline__ float tanhfast(float x) {
    float e = __expf(2.0f * x);
    return 1.0f - 2.0f / (e + 1.0f);
}

union pcast { u64 u; float2 f; };
// h stores: agent-scope -> LLC-visible once vmcnt drains (r7/r9-proven protocol)
__device__ __forceinline__ void gstore2(float2* p, float2 v) {
    pcast c; c.f = v;
    __hip_atomic_store((u64*)p, c.u, __ATOMIC_RELAXED, __HIP_MEMORY_SCOPE_AGENT);
}

// PER-WAVE stream barrier: drain own stores, release flag, poll 256 flags
// (4/lane), acquire fence (L1/L2 inv -> fresh h on cached loads).
// No __syncthreads: waves/streams proceed independently.
__device__ __forceinline__ void wbar(u32* fS, int wgid, int lane, u32 phase) {
    asm volatile("s_waitcnt vmcnt(0)" ::: "memory");
    if (lane == 0)
        __hip_atomic_store(&fS[wgid], phase, __ATOMIC_RELEASE, __HIP_MEMORY_SCOPE_AGENT);
    const u32* f = fS + lane;
    for (;;) {
        bool d = (__hip_atomic_load(f,       __ATOMIC_RELAXED, __HIP_MEMORY_SCOPE_AGENT) >= phase)
              && (__hip_atomic_load(f + 64,  __ATOMIC_RELAXED, __HIP_MEMORY_SCOPE_AGENT) >= phase)
              && (__hip_atomic_load(f + 128, __ATOMIC_RELAXED, __HIP_MEMORY_SCOPE_AGENT) >= phase)
              && (__hip_atomic_load(f + 192, __ATOMIC_RELAXED, __HIP_MEMORY_SCOPE_AGENT) >= phase);
        if (__all(d)) break;
        __builtin_amdgcn_s_sleep(2);
    }
    __builtin_amdgcn_fence(__ATOMIC_ACQUIRE, "agent");
}

// Weight LDS: [row 0..23][kq 0..3][136 = 128 + 8 pad] floats.
// row = u*12 + m*4 + g  (m: 0=l1_Wh, 1=l2_Wx, 2=l2_Wh). Row stride 544 (17 KB.. 544*4B),
// 544%32==0 (row bank-invariant); kq*136 -> banks 8kq..8kq+3: 4 disjoint sets;
// (u,kq) twin rows alias 2-way only (free).
#define WROWS 24
#define WSTR  544

__global__ void __launch_bounds__(NTHR, 2)
lstm_fused(const float* __restrict__ input,
           const float* __restrict__ l1_Wx, const float* __restrict__ l1_bx,
           const float* __restrict__ l1_Wh, const float* __restrict__ l1_bh,
           const float* __restrict__ l2_Wx, const float* __restrict__ l2_bx,
           const float* __restrict__ l2_Wh, const float* __restrict__ l2_bh,
           const float* __restrict__ fc1_W, const float* __restrict__ fc1_b,
           const float* __restrict__ fc2_W, const float* __restrict__ fc2_b,
           const float* __restrict__ fc3_W, const float* __restrict__ fc3_b,
           float* __restrict__ out, float* __restrict__ ws)
{
    __shared__ float wlds[WROWS * WSTR];     // 52 KB weights
    __shared__ float wx1l[8 * 20];           // l1_Wx rows (2u x 4g), pad 20
    __shared__ float fcb[Hh + 256 + 128];    // FC head scratch

    cg::grid_group grid = cg::this_grid();
    const int wgid = blockIdx.x;
    const int jb = wgid * 2;
    const int tid = threadIdx.x;

    const int sid  = __builtin_amdgcn_readfirstlane(tid >> 6);  // stream / wave id
    const int lane = tid & 63;
    const int u    = lane >> 5;          // unit select (0/1)
    const int kq   = (lane >> 3) & 3;    // K quarter
    const int bp   = lane & 7;           // batch sub-block
    const int b0   = sid * 32 + bp * 4;  // first of this lane's 4 batches
    const int j    = jb + u;             // owned unit

    float2* PA = (float2*)ws;            // P[j][b] = (h1[t], h2[t-1]) pairs
    float2* PB = PA + (size_t)Hh * Bb;
    u32* flags = (u32*)(PB + (size_t)Hh * Bb);   // [8 streams][256 wg]
    u32* fS = flags + sid * 256;

    // ---- reset ALL stream flags for this wg, then the only cg sync ----
    if (tid < 8)
        __hip_atomic_store(&flags[tid * 256 + wgid], 0u,
                           __ATOMIC_RELAXED, __HIP_MEMORY_SCOPE_AGENT);
    grid.sync();

    // ---- stage weights into LDS (once) ----
    for (int idx = tid; idx < WROWS * Hh; idx += NTHR) {
        const int ri = idx >> 9, k = idx & 511;
        const int uu = ri / 12, rr = ri - uu * 12;
        const int m = rr >> 2, g = rr & 3;
        const float* src = (m == 0) ? l1_Wh : (m == 1) ? l2_Wx : l2_Wh;
        wlds[ri * WSTR + (k >> 7) * 136 + (k & 127)] =
            src[(size_t)(g * Hh + jb + uu) * Hh + k];
    }
    if (tid < 8 * INx) {
        const int r = tid / INx, i = tid - r * INx;
        const int uu = r >> 2, g = r & 3;
        wx1l[r * 20 + i] = l1_Wx[(size_t)(g * Hh + jb + uu) * INx + i];
    }
    float b1r[4], b2r[4];
    #pragma unroll
    for (int g = 0; g < 4; ++g) {
        const int row = g * Hh + j;
        b1r[g] = l1_bx[row] + l1_bh[row];
        b2r[g] = l2_bx[row] + l2_bh[row];
    }
    __syncthreads();   // weights staged (before any wave enters its loop)

    // ---- prologue (kq==0 lanes): P = (h1[0], h2[-1]=0) for 4 batches ----
    float c1[4], c2[4];
    #pragma unroll
    for (int b = 0; b < 4; ++b) { c1[b] = 0.f; c2[b] = 0.f; }
    if (kq == 0) {
        #pragma unroll
        for (int b = 0; b < 4; ++b) {
            const float* xr = input + (size_t)(b0 + b) * Tt * INx;
            float s[4];
            #pragma unroll
            for (int g = 0; g < 4; ++g) {
                float acc = b1r[g];
                #pragma unroll
                for (int i = 0; i < INx; ++i) acc += xr[i] * wx1l[(u * 4 + g) * 20 + i];
                s[g] = acc;
            }
            c1[b] = sigf(s[0]) * tanhfast(s[2]);     // f*0 + i*g
            gstore2(&PA[(size_t)j * Bb + b0 + b],
                    make_float2(sigf(s[3]) * tanhfast(c1[b]), 0.f));
        }
    }
    wbar(fS, wgid, lane, 1u);

    const float2* Pc = PA; float2* Pn = PB;
    const float* wk0 = wlds + (u * 12) * WSTR + kq * 136;   // this lane's weight base

    for (int t = 0; t < Tt; ++t) {
        const bool doL1 = (t < Tt - 1);

        float a1[4][4], a2[4][4];    // [gate][batch]; a2 merges l2_Wx & l2_Wh
        #pragma unroll
        for (int g = 0; g < 4; ++g)
            #pragma unroll
            for (int b = 0; b < 4; ++b) { a1[g][b] = 0.f; a2[g][b] = 0.f; }

        // lane float4 base: float2 idx = k*256 + b0 -> float4 idx = k*128 + b0/2
        const float4* hp = (const float4*)Pc + (size_t)(kq * 128) * 128 + (b0 >> 1);

        #pragma unroll 1
        for (int c = 0; c < 32; ++c) {
            float4 HA[4], HB[4];               // 4 k's x 4 batches of (h1,h2) pairs
            #pragma unroll
            for (int kk = 0; kk < 4; ++kk) {
                HA[kk] = hp[(size_t)(c * 4 + kk) * 128];
                HB[kk] = hp[(size_t)(c * 4 + kk) * 128 + 1];
            }
            const float* wk = wk0 + c * 4;
            #pragma unroll
            for (int g = 0; g < 4; ++g) {
                const float4 w1 = *reinterpret_cast<const float4*>(wk + (0 + g) * WSTR);
                const float4 w2 = *reinterpret_cast<const float4*>(wk + (4 + g) * WSTR);
                const float4 w3 = *reinterpret_cast<const float4*>(wk + (8 + g) * WSTR);
                // batches: HA .x/.y = b0 (h1,h2), .z/.w = b0+1; HB: b0+2, b0+3
                a1[g][0] += HA[0].x*w1.x + HA[1].x*w1.y + HA[2].x*w1.z + HA[3].x*w1.w;
                a1[g][1] += HA[0].z*w1.x + HA[1].z*w1.y + HA[2].z*w1.z + HA[3].z*w1.w;
                a1[g][2] += HB[0].x*w1.x + HB[1].x*w1.y + HB[2].x*w1.z + HB[3].x*w1.w;
                a1[g][3] += HB[0].z*w1.x + HB[1].z*w1.y + HB[2].z*w1.z + HB[3].z*w1.w;
                a2[g][0] += HA[0].x*w2.x + HA[1].x*w2.y + HA[2].x*w2.z + HA[3].x*w2.w
                          + HA[0].y*w3.x + HA[1].y*w3.y + HA[2].y*w3.z + HA[3].y*w3.w;
                a2[g][1] += HA[0].z*w2.x + HA[1].z*w2.y + HA[2].z*w2.z + HA[3].z*w2.w
                          + HA[0].w*w3.x + HA[1].w*w3.y + HA[2].w*w3.z + HA[3].w*w3.w;
                a2[g][2] += HB[0].x*w2.x + HB[1].x*w2.y + HB[2].x*w2.z + HB[3].x*w2.w
                          + HB[0].y*w3.x + HB[1].y*w3.y + HB[2].y*w3.z + HB[3].y*w3.w;
                a2[g][3] += HB[0].z*w2.x + HB[1].z*w2.y + HB[2].z*w2.z + HB[3].z*w2.w
                          + HB[0].w*w3.x + HB[1].w*w3.y + HB[2].w*w3.z + HB[3].w*w3.w;
            }
        }

        // ---- in-wave K-reduce over the 4 kq groups (lane bits 3,4) ----
        #pragma unroll
        for (int g = 0; g < 4; ++g) {
            #pragma unroll
            for (int b = 0; b < 4; ++b) {
                float v = a1[g][b]; v += __shfl_xor(v, 8, 64); v += __shfl_xor(v, 16, 64); a1[g][b] = v;
                float w = a2[g][b]; w += __shfl_xor(w, 8, 64); w += __shfl_xor(w, 16, 64); a2[g][b] = w;
            }
        }

        // ---- finish (kq==0 lanes: unit j, 4 batches) ----
        if (kq == 0) {
            #pragma unroll
            for (int b = 0; b < 4; ++b) {
                const int bb = b0 + b;
                float h1v = 0.f;
                if (doL1) {
                    const float* xr = input + ((size_t)bb * Tt + t + 1) * INx;
                    float s1[4];
                    #pragma unroll
                    for (int g = 0; g < 4; ++g) {
                        float acc = a1[g][b] + b1r[g];
                        #pragma unroll
                        for (int i = 0; i < INx; ++i) acc += xr[i] * wx1l[(u * 4 + g) * 20 + i];
                        s1[g] = acc;
                    }
                    const float ig = sigf(s1[0]), fg = sigf(s1[1]);
                    const float gg = tanhfast(s1[2]), og = sigf(s1[3]);
                    c1[b] = fg * c1[b] + ig * gg;
                    h1v = og * tanhfast(c1[b]);
                }
                const float ig = sigf(a2[0][b] + b2r[0]);
                const float fg = sigf(a2[1][b] + b2r[1]);
                const float gg = tanhfast(a2[2][b] + b2r[2]);
                const float og = sigf(a2[3][b] + b2r[3]);
                c2[b] = fg * c2[b] + ig * gg;
                gstore2(&Pn[(size_t)j * Bb + bb], make_float2(h1v, og * tanhfast(c2[b])));
            }
        }

        wbar(fS, wgid, lane, (u32)(t + 2));

        const float2* tp = Pc; Pc = Pn; Pn = (float2*)tp;
    }
    // final h2 = Pc[.].y (all waves did the same number of swaps)

    // ---- join local waves; each wave's own stream is globally done; fence for FC ----
    __syncthreads();
    __builtin_amdgcn_fence(__ATOMIC_ACQUIRE, "agent");

    // ---------- FC head: WG wgid handles batch wgid ----------
    float* hh  = fcb;
    float* a1s = fcb + Hh;
    float* a2s = fcb + Hh + 256;
    hh[tid] = Pc[(size_t)tid * Bb + wgid].y;
    __syncthreads();
    if (tid < 256) {
        float acc = fc1_b[tid];
        const float* wr = fc1_W + (size_t)tid * Hh;
        for (int i = 0; i < Hh; ++i) acc += wr[i] * hh[i];
        a1s[tid] = fmaxf(acc, 0.0f);
    }
    __syncthreads();
    if (tid < 128) {
        float acc = fc2_b[tid];
        const float* wr = fc2_W + (size_t)tid * 256;
        for (int i = 0; i < 256; ++i) acc += wr[i] * a1s[i];
        a2s[tid] = fmaxf(acc, 0.0f);
    }
    __syncthreads();
    if (tid == 0) {
        float acc = fc3_b[0];
        for (int i = 0; i < 128; ++i) acc += fc3_W[i] * a2s[i];
        out[wgid] = acc;
    }
}

extern "C" void kernel_launch(void* const* d_in, const int* in_sizes, int n_in,
                              void* d_out, int out_size, void* d_ws, size_t ws_size,
                              hipStream_t stream)
{
    (void)in_sizes; (void)n_in; (void)out_size; (void)ws_size;

    const float* input = (const float*)d_in[0];
    const float* l1_Wx = (const float*)d_in[1];
    const float* l1_bx = (const float*)d_in[2];
    const float* l1_Wh = (const float*)d_in[3];
    const float* l1_bh = (const float*)d_in[4];
    const float* l2_Wx = (const float*)d_in[5];
    const float* l2_bx = (const float*)d_in[6];
    const float* l2_Wh = (const float*)d_in[7];
    const float* l2_bh = (const float*)d_in[8];
    const float* fc1_W = (const float*)d_in[9];
    const float* fc1_b = (const float*)d_in[10];
    const float* fc2_W = (const float*)d_in[11];
    const float* fc2_b = (const float*)d_in[12];
    const float* fc3_W = (const float*)d_in[13];
    const float* fc3_b = (const float*)d_in[14];
    float* out = (float*)d_out;
    float* ws  = (float*)d_ws;

    void* args[] = {
        &input,
        &l1_Wx, &l1_bx, &l1_Wh, &l1_bh,
        &l2_Wx, &l2_bx, &l2_Wh, &l2_bh,
        &fc1_W, &fc1_b, &fc2_W, &fc2_b, &fc3_W, &fc3_b,
        &out, &ws
    };
    hipLaunchCooperativeKernel((void*)lstm_fused, dim3(NWG), dim3(NTHR), args, 0, stream);
}